// Round 5
// baseline (325.874 us; speedup 1.0000x reference)
//
#include <hip/hip_runtime.h>

// Maxwell: gamma_{n+1} = (1-2dt_n) gamma_n + 2 dt_n eps_n ; sigma_t = 3 eps_t - 2 gamma_t, sigma_0=0.
//
// Block-per-row-PAIR with cross-pair software prefetch.
//  - 256 threads, each thread owns 8 contiguous timesteps of TWO rows (A,B):
//    fully coalesced float4 loads, 8 KB per wave in flight.
//  - Two independent affine (P,Q) shfl-scans interleaved -> 2x ILP in the
//    dependent ds_bpermute chain; one barrier serves both rows.
//  - Each block loops over RPB=4 rows (2 pairs), prefetching the next pair's
//    8 float4 loads into registers before scanning the current pair, so HBM
//    latency hides under scan latency.
//  - Nontemporal stores (output is never re-read).

typedef float v4f __attribute__((ext_vector_type(4)));

#define T_LEN 2048
#define RPB 4   // rows per block (2 pairs); grid = nrows / RPB

__global__ __launch_bounds__(256) void maxwell_pipe_kernel(
    const float* __restrict__ eps_g, const float* __restrict__ dt_g,
    float* __restrict__ out_g, int nrows)
{
    const int tid  = threadIdx.x;
    const int lane = tid & 63;
    const int wid  = tid >> 6;
    const long row0 = (long)blockIdx.x * RPB;
    const long tb   = (long)tid * 8;

    __shared__ float sP[2][2][4], sQ[2][2][4];   // [parity][row-in-pair][wave]

    // Load pair 0 (rows row0, row0+1).
    v4f eA0, eA1, dA0, dA1, eB0, eB1, dB0, dB1;
    {
        const float* pA = eps_g + row0 * T_LEN + tb;
        const float* qA = dt_g  + row0 * T_LEN + tb;
        eA0 = *(const v4f*)pA;           eA1 = *(const v4f*)(pA + 4);
        eB0 = *(const v4f*)(pA + T_LEN); eB1 = *(const v4f*)(pA + T_LEN + 4);
        dA0 = *(const v4f*)qA;           dA1 = *(const v4f*)(qA + 4);
        dB0 = *(const v4f*)(qA + T_LEN); dB1 = *(const v4f*)(qA + T_LEN + 4);
    }

    #pragma unroll
    for (int it = 0; it < RPB / 2; ++it) {
        const long rA = row0 + 2 * it;

        // ---- Prefetch next pair (issue loads; do NOT consume yet) ----
        v4f neA0, neA1, ndA0, ndA1, neB0, neB1, ndB0, ndB1;
        if (it + 1 < RPB / 2) {
            const float* pA = eps_g + (rA + 2) * T_LEN + tb;
            const float* qA = dt_g  + (rA + 2) * T_LEN + tb;
            neA0 = *(const v4f*)pA;           neA1 = *(const v4f*)(pA + 4);
            neB0 = *(const v4f*)(pA + T_LEN); neB1 = *(const v4f*)(pA + T_LEN + 4);
            ndA0 = *(const v4f*)qA;           ndA1 = *(const v4f*)(qA + 4);
            ndB0 = *(const v4f*)(qA + T_LEN); ndB1 = *(const v4f*)(qA + T_LEN + 4);
        }

        // ---- Unpack current pair (all static indices after SROA) ----
        float eA[8] = {eA0.x,eA0.y,eA0.z,eA0.w, eA1.x,eA1.y,eA1.z,eA1.w};
        float dA[8] = {dA0.x,dA0.y,dA0.z,dA0.w, dA1.x,dA1.y,dA1.z,dA1.w};
        float eB[8] = {eB0.x,eB0.y,eB0.z,eB0.w, eB1.x,eB1.y,eB1.z,eB1.w};
        float dB[8] = {dB0.x,dB0.y,dB0.z,dB0.w, dB1.x,dB1.y,dB1.z,dB1.w};

        // ---- Compose each thread's 8 transitions: g -> P*g + Q ----
        float PA = 1.0f, QA = 0.0f, PB = 1.0f, QB = 0.0f;
        #pragma unroll
        for (int k = 0; k < 8; ++k) {
            const float adA = 2.0f * dA[k];
            const float adB = 2.0f * dB[k];
            QA = fmaf(1.0f - adA, QA, adA * eA[k]);  PA *= (1.0f - adA);
            QB = fmaf(1.0f - adB, QB, adB * eB[k]);  PB *= (1.0f - adB);
        }

        // ---- Inclusive wave scan, two independent chains interleaved ----
        #pragma unroll
        for (int dd = 1; dd < 64; dd <<= 1) {
            const float PpA = __shfl_up(PA, dd), QpA = __shfl_up(QA, dd);
            const float PpB = __shfl_up(PB, dd), QpB = __shfl_up(QB, dd);
            if (lane >= dd) {
                QA = fmaf(PA, QpA, QA);  PA *= PpA;
                QB = fmaf(PB, QpB, QB);  PB *= PpB;
            }
        }

        // ---- Cross-wave combine (one barrier per pair, parity-buffered) ----
        if (lane == 63) {
            sP[it & 1][0][wid] = PA;  sQ[it & 1][0][wid] = QA;
            sP[it & 1][1][wid] = PB;  sQ[it & 1][1][wid] = QB;
        }
        __syncthreads();
        float QwA = 0.0f, QwB = 0.0f;   // gamma_0 = 0 -> only Q survives
        for (int w = 0; w < wid; ++w) {
            QwA = fmaf(sP[it & 1][0][w], QwA, sQ[it & 1][0][w]);
            QwB = fmaf(sP[it & 1][1][w], QwB, sQ[it & 1][1][w]);
        }

        // ---- Exclusive prefix within wave -> incoming gamma ----
        float PeA = __shfl_up(PA, 1), QeA = __shfl_up(QA, 1);
        float PeB = __shfl_up(PB, 1), QeB = __shfl_up(QB, 1);
        if (lane == 0) { PeA = 1.0f; QeA = 0.0f; PeB = 1.0f; QeB = 0.0f; }
        float gA = fmaf(PeA, QwA, QeA);
        float gB = fmaf(PeB, QwB, QeB);

        // ---- Replay 8 local steps; store nontemporal float4 ----
        float oA[8], oB[8];
        oA[0] = fmaf(3.0f, eA[0], -2.0f * gA);
        oB[0] = fmaf(3.0f, eB[0], -2.0f * gB);
        #pragma unroll
        for (int k = 1; k < 8; ++k) {
            gA = fmaf(2.0f * dA[k-1], eA[k-1] - gA, gA);
            gB = fmaf(2.0f * dB[k-1], eB[k-1] - gB, gB);
            oA[k] = fmaf(3.0f, eA[k], -2.0f * gA);
            oB[k] = fmaf(3.0f, eB[k], -2.0f * gB);
        }
        if (tid == 0) { oA[0] = 0.0f; oB[0] = 0.0f; }  // sigma_0 = 0

        float* outA = out_g + rA * T_LEN + tb;
        v4f wA0 = {oA[0], oA[1], oA[2], oA[3]};
        v4f wA1 = {oA[4], oA[5], oA[6], oA[7]};
        v4f wB0 = {oB[0], oB[1], oB[2], oB[3]};
        v4f wB1 = {oB[4], oB[5], oB[6], oB[7]};
        __builtin_nontemporal_store(wA0, (v4f*)outA);
        __builtin_nontemporal_store(wA1, (v4f*)(outA + 4));
        __builtin_nontemporal_store(wB0, (v4f*)(outA + T_LEN));
        __builtin_nontemporal_store(wB1, (v4f*)(outA + T_LEN + 4));

        // ---- Rotate prefetch into current ----
        if (it + 1 < RPB / 2) {
            eA0 = neA0; eA1 = neA1; dA0 = ndA0; dA1 = ndA1;
            eB0 = neB0; eB1 = neB1; dB0 = ndB0; dB1 = ndB1;
        }
    }
}

extern "C" void kernel_launch(void* const* d_in, const int* in_sizes, int n_in,
                              void* d_out, int out_size, void* d_ws, size_t ws_size,
                              hipStream_t stream) {
    const float* strains = (const float*)d_in[0];
    const float* dts     = (const float*)d_in[1];
    float* out           = (float*)d_out;

    const int nrows  = in_sizes[0] / T_LEN;        // 16384
    const int blocks = nrows / RPB;                // 4096
    maxwell_pipe_kernel<<<blocks, 256, 0, stream>>>(strains, dts, out, nrows);
}